// Round 15
// baseline (208.503 us; speedup 1.0000x reference)
//
#include <hip/hip_runtime.h>
#include <math.h>

// ---------------------------------------------------------------------------
// CommunityTrustGNN: 2-layer GraphSAGE (mean agg) + trust MLP head
// N=100000 nodes, E=1600000 edges, dims 64 -> 64 -> 32 -> (16 -> 1)
//
// Round 26 = round-25 (verified 206.6us) with pipelined atomic-fill loops:
//  * k_m1 scatter fill: was 8x serialized {LDS atomicAdd -> dependent
//    store} round-trips on the block critical path. Now: issue all 8
//    independent atomics back-to-back, collect pos[], then all stores
//    (slot assignment is permutation-equivalent; numerics identical).
//  * k_m2 CSR: pp[] read ONCE into regs (reused for histogram AND fill —
//    deletes the 2nd 6.4MB grid-wide pairs read); fill pipelined same way.
//  * everything else: round-25 verbatim.
// ---------------------------------------------------------------------------

#define NBUCK   1563     // ceil(100000/64) buckets of 64 dst nodes
#define BCAP    1536     // bucket capacity (mean 1024, +16 sigma)
#define BKCHUNK 4096     // edges per bucket-chunk block in M1

typedef __attribute__((ext_vector_type(8))) __bf16 bf16x8;
typedef __attribute__((ext_vector_type(4))) float  f32x4;

union BU { bf16x8 v; unsigned short u[8]; };

// bf16 helpers (round-to-nearest-even pack, exact unpack)
__device__ inline unsigned short f2bf(float x) {
    unsigned u = __float_as_uint(x);
    unsigned r = u + 0x7fffu + ((u >> 16) & 1u);
    return (unsigned short)(r >> 16);
}
__device__ inline float bflo(unsigned u) { return __uint_as_float(u << 16); }
__device__ inline float bfhi(unsigned u) { return __uint_as_float(u & 0xffff0000u); }
__device__ inline float bf2f(unsigned short h) { return __uint_as_float((unsigned)h << 16); }
// pack value as (bf16hi | bf16lo<<16) for split-bf16 A-fragments
__device__ inline unsigned packhl(float x) {
    unsigned short h = f2bf(x);
    unsigned short l = f2bf(x - bf2f(h));
    return (unsigned)h | ((unsigned)l << 16);
}

// --- W: precompute fragment-ordered bf16 hi/lo weight planes; zero gcnt -----
__global__ __launch_bounds__(256) void k_w(
    const float* __restrict__ Wl1, const float* __restrict__ Wr1,
    const float* __restrict__ Wl2, const float* __restrict__ Wr2,
    unsigned short* __restrict__ Wf, int* __restrict__ gcnt)
{
    int tid = threadIdx.x;
    for (int i = tid; i < 2048; i += 256) gcnt[i] = 0;
    for (int idx = tid; idx < 1536; idx += 256) {
        unsigned short hi8[8], lo8[8];
        int base;
        if (idx < 1024) {
            int q = idx >> 6;                 // 0..15: (pass,nf,kf)
            int l = idx & 63;
            int pass = q >> 3, nf = (q >> 1) & 3, kf = q & 1;
            const float* W = pass ? Wr1 : Wl1;
            int col  = nf * 16 + (l & 15);
            int krow = kf * 32 + (l >> 4) * 8;
            #pragma unroll
            for (int e = 0; e < 8; ++e) {
                float w = W[(krow + e) * 64 + col];
                unsigned short h = f2bf(w);
                hi8[e] = h;
                lo8[e] = f2bf(w - bf2f(h));
            }
            base = (q * 2) * 512 + l * 8;
        } else {
            int i2 = idx - 1024;
            int q2 = i2 >> 6;                 // 0..7: (ntile,kf)
            int l = i2 & 63;
            int ntile = q2 >> 1, kf = q2 & 1;
            int col  = ntile * 16 + (l & 15); // 0..63 over concat(Wl2,Wr2)
            const float* W = (col < 32) ? Wl2 : Wr2;
            int c = col & 31;
            int krow = kf * 32 + (l >> 4) * 8;
            #pragma unroll
            for (int e = 0; e < 8; ++e) {
                float w = W[(krow + e) * 32 + c];
                unsigned short h = f2bf(w);
                hi8[e] = h;
                lo8[e] = f2bf(w - bf2f(h));
            }
            base = (32 + q2 * 2) * 512 + l * 8;
        }
        #pragma unroll
        for (int e = 0; e < 8; ++e) {
            Wf[base + e]       = hi8[e];
            Wf[base + 512 + e] = lo8[e];
        }
    }
}

// --- M1: interleaved gemm1 tile-pairs + bucket-scatter chunks ---------------
// blockIdx%3==2 -> scatter chunk (blockIdx/3); else tile-pair p=2*(b/3)+(b%3),
// tiles 2p+(wave>>2).
__global__ __launch_bounds__(512) void k_m1(
    const float* __restrict__ x,
    const unsigned short* __restrict__ Wf, const float* __restrict__ b1,
    unsigned* __restrict__ u16b, float* __restrict__ v,
    const int* __restrict__ src, const int* __restrict__ dst,
    int* __restrict__ gcnt, unsigned* __restrict__ pairs,
    int N, int E, int GB, int BKB)
{
    __shared__ int hist[NBUCK];           // 6252B (scatter blocks only)
    int tid = threadIdx.x;
    int g = blockIdx.x / 3, r3 = blockIdx.x % 3;

    if (r3 == 2) {
        // ---------------- bucket-scatter path (512 thr, 8 edges/thr) ------
        if (g >= BKB) return;
        int e0 = g * BKCHUNK;
        int e1 = min(e0 + BKCHUNK, E);

        // load edges once into regs
        int d[8], s[8], ne = 0;
        for (int e = e0 + tid; e < e1; e += 512) {
            d[ne] = dst[e];
            s[ne] = src[e];
            ++ne;
        }

        for (int i = tid; i < NBUCK; i += 512) hist[i] = 0;
        __syncthreads();
        #pragma unroll
        for (int k = 0; k < 8; ++k)
            if (k < ne) atomicAdd(&hist[((unsigned)d[k]) >> 6], 1);
        __syncthreads();
        // pipelined reservation: 4 independent atomics issued back-to-back
        int cnt[4], base[4];
        #pragma unroll
        for (int t = 0; t < 4; ++t) {
            int i = tid + t * 512;
            cnt[t] = (i < NBUCK) ? hist[i] : 0;
        }
        #pragma unroll
        for (int t = 0; t < 4; ++t) {
            int i = tid + t * 512;
            base[t] = (i < NBUCK) ? atomicAdd(&gcnt[i], cnt[t]) : 0;
        }
        #pragma unroll
        for (int t = 0; t < 4; ++t) {
            int i = tid + t * 512;
            if (i < NBUCK) hist[i] = i * BCAP + base[t];
        }
        __syncthreads();
        // pipelined fill: all atomics issued, THEN all stores (no per-edge
        // atomic->store round-trip on the critical path)
        int bb[8], pos[8];
        #pragma unroll
        for (int k = 0; k < 8; ++k)
            bb[k] = (k < ne) ? (int)(((unsigned)d[k]) >> 6) : 0;
        #pragma unroll
        for (int k = 0; k < 8; ++k)
            if (k < ne) pos[k] = atomicAdd(&hist[bb[k]], 1);
        #pragma unroll
        for (int k = 0; k < 8; ++k)
            if (k < ne && pos[k] < (bb[k] + 1) * BCAP)  // overflow clamp
                pairs[pos[k]] = (unsigned)s[k] | ((unsigned)(d[k] & 63) << 17);
        return;
    }

    // ---------------- gemm1 path: split-bf16 MFMA, no LDS, 2 tiles --------
    int p = 2 * g + r3;
    int wave = tid >> 6;
    int tile = 2 * p + (wave >> 2);
    if (tile >= GB) return;
    int nblk = tile * 64;

    int l  = tid & 63;
    int wv = wave & 3;                  // row-block within tile
    int la = l & 15,   g4 = l >> 4;     // col-within-16, k-group
    int arow = nblk + wv * 16 + la;     // A row for this lane
    bool rowOK = (arow < N);

    // A fragments from global (16 rows x 128B contiguous per k-half)
    BU ahi[2], alo[2];
    #pragma unroll
    for (int kf = 0; kf < 2; ++kf) {
        float xv[8];
        if (rowOK) {
            const float* xp = &x[(size_t)arow * 64 + kf * 32 + g4 * 8];
            float4 p0 = *(const float4*)xp;
            float4 p1 = *(const float4*)(xp + 4);
            xv[0] = p0.x; xv[1] = p0.y; xv[2] = p0.z; xv[3] = p0.w;
            xv[4] = p1.x; xv[5] = p1.y; xv[6] = p1.z; xv[7] = p1.w;
        } else {
            #pragma unroll
            for (int e = 0; e < 8; ++e) xv[e] = 0.0f;
        }
        #pragma unroll
        for (int e = 0; e < 8; ++e) {
            unsigned short h = f2bf(xv[e]);
            ahi[kf].u[e] = h;
            alo[kf].u[e] = f2bf(xv[e] - bf2f(h));
        }
    }

    unsigned short* u16 = (unsigned short*)u16b;

    #pragma unroll
    for (int pass = 0; pass < 2; ++pass) {
        #pragma unroll
        for (int nf = 0; nf < 4; ++nf) {
            int n0 = nf * 16;
            f32x4 acc = {0.f, 0.f, 0.f, 0.f};
            #pragma unroll
            for (int kf = 0; kf < 2; ++kf) {
                int q2 = ((pass * 4 + nf) * 2 + kf) * 2;
                bf16x8 bhi = *(const bf16x8*)&Wf[(q2 + 0) * 512 + l * 8];
                bf16x8 blo = *(const bf16x8*)&Wf[(q2 + 1) * 512 + l * 8];
                acc = __builtin_amdgcn_mfma_f32_16x16x32_bf16(ahi[kf].v, bhi, acc, 0, 0, 0);
                acc = __builtin_amdgcn_mfma_f32_16x16x32_bf16(alo[kf].v, bhi, acc, 0, 0, 0);
                acc = __builtin_amdgcn_mfma_f32_16x16x32_bf16(ahi[kf].v, blo, acc, 0, 0, 0);
            }
            // D: col = la, row = g4*4 + r  (m89-verified layout)
            if (pass == 0) {
                #pragma unroll
                for (int rr = 0; rr < 4; ++rr) {
                    int nd = nblk + wv * 16 + g4 * 4 + rr;
                    if (nd < N)
                        u16[(size_t)nd * 64 + n0 + la] = f2bf(acc[rr]);
                }
            } else {
                float bb = b1[n0 + la];
                #pragma unroll
                for (int rr = 0; rr < 4; ++rr) {
                    int nd = nblk + wv * 16 + g4 * 4 + rr;
                    if (nd < N)
                        v[(size_t)nd * 64 + n0 + la] = acc[rr] + bb;
                }
            }
        }
    }
}

// --- M2: local-CSR (persisted) + agg1 + gemm2(MFMA). Block = 64-node bucket.
// CSR: pp read ONCE into regs; histogram + pipelined fill reuse the regs.
// Phase A: 32 groups x 16 lanes x 2 nodes; uint2 row-slice per lane (4
//          features owned per lane), serial neighbor walk, no cross-lane.
__global__ __launch_bounds__(512) void k_m2(
    const unsigned* __restrict__ pairs, const int* __restrict__ gcnt,
    const unsigned* __restrict__ u16b, const float* __restrict__ v,
    const unsigned short* __restrict__ Wf, const float* __restrict__ b2,
    unsigned* __restrict__ P16b, float* __restrict__ Qout,
    int2* __restrict__ nodeOff, int* __restrict__ adjG, int N)
{
    __shared__ unsigned sHu[64 * 76]; // 19456B packed h tile, stride 76
    __shared__ int   sAdj[BCAP];      // 6144B
    __shared__ int   sOff[65];
    __shared__ int   sCur[64];
    int tid = threadIdx.x;
    int b = blockIdx.x;
    int nodeBase = b * 64;
    int base = b * BCAP;
    int count = min(gcnt[b], BCAP);
    const unsigned* pp = pairs + (size_t)b * BCAP;

    if (tid < 64) sCur[tid] = 0;
    // ---- read this thread's pair entries ONCE ----
    unsigned ew[3]; int nw = 0;
    for (int j = tid; j < count; j += 512) ew[nw++] = pp[j];
    __syncthreads();

    // ---- local CSR: histogram -> scan -> pipelined fill ----
    #pragma unroll
    for (int k = 0; k < 3; ++k)
        if (k < nw) atomicAdd(&sCur[(ew[k] >> 17) & 63], 1);
    __syncthreads();
    if (tid < 64) {
        int c = sCur[tid];
        int incl = c;
        #pragma unroll
        for (int off = 1; off < 64; off <<= 1) {
            int t = __shfl_up(incl, off);
            if (tid >= off) incl += t;
        }
        sOff[tid] = incl - c;
        if (tid == 63) sOff[64] = incl;
    }
    __syncthreads();
    if (tid < 64) {
        sCur[tid] = sOff[tid];
        int node = nodeBase + tid;
        if (node < N)
            nodeOff[node] = make_int2(base + sOff[tid], sOff[tid + 1] - sOff[tid]);
    }
    __syncthreads();
    int ps[3];
    #pragma unroll
    for (int k = 0; k < 3; ++k)
        if (k < nw) ps[k] = atomicAdd(&sCur[(ew[k] >> 17) & 63], 1);
    #pragma unroll
    for (int k = 0; k < 3; ++k)
        if (k < nw) sAdj[ps[k]] = (int)(ew[k] & 0x1FFFFu);
    __syncthreads();
    // persist adj for k_a2 (coalesced burst)
    for (int j = tid; j < count; j += 512) adjG[base + j] = sAdj[j];

    // ---- Phase A: 32 groups x 16 lanes, 2 nodes each, uint2 serial walk ----
    int gr = tid >> 4, lane = tid & 15;
    for (int r = 0; r < 2; ++r) {
        int nl = gr * 2 + r;
        int node = nodeBase + nl;
        float h0 = 0.0f, h1 = 0.0f, h2 = 0.0f, h3 = 0.0f;
        if (node < N) {
            int beg = sOff[nl], end = sOff[nl + 1];
            float a0[4] = {0,0,0,0}, a1[4] = {0,0,0,0};
            float a2[4] = {0,0,0,0}, a3[4] = {0,0,0,0};
            unsigned fo = 2u * (unsigned)lane;
            int i = beg;
            for (; i + 4 <= end; i += 4) {
                int s[4];
                #pragma unroll
                for (int j = 0; j < 4; ++j) s[j] = sAdj[i + j];
                #pragma unroll
                for (int j = 0; j < 4; ++j) {
                    uint2 w = *(const uint2*)&u16b[(unsigned)s[j] * 32u + fo];
                    a0[j] += bflo(w.x); a1[j] += bfhi(w.x);
                    a2[j] += bflo(w.y); a3[j] += bfhi(w.y);
                }
            }
            for (; i < end; ++i) {
                uint2 w = *(const uint2*)&u16b[(unsigned)sAdj[i] * 32u + fo];
                a0[0] += bflo(w.x); a1[0] += bfhi(w.x);
                a2[0] += bflo(w.y); a3[0] += bfhi(w.y);
            }
            float m0 = (a0[0] + a0[1]) + (a0[2] + a0[3]);
            float m1 = (a1[0] + a1[1]) + (a1[2] + a1[3]);
            float m2 = (a2[0] + a2[1]) + (a2[2] + a2[3]);
            float m3 = (a3[0] + a3[1]) + (a3[2] + a3[3]);
            int deg = end - beg;
            float invd = (deg > 0) ? 1.0f / (float)deg : 1.0f;
            float4 vv = *(const float4*)&v[(size_t)node * 64 + 4 * lane];
            h0 = fmaxf(m0 * invd + vv.x, 0.0f);
            h1 = fmaxf(m1 * invd + vv.y, 0.0f);
            h2 = fmaxf(m2 * invd + vv.z, 0.0f);
            h3 = fmaxf(m3 * invd + vv.w, 0.0f);
        }
        // features 4*lane .. 4*lane+3 packed hi|lo
        *(uint4*)&sHu[nl * 76 + 4 * lane] =
            make_uint4(packhl(h0), packhl(h1), packhl(h2), packhl(h3));
    }
    __syncthreads();

    // ---- Phase B: 64x64 split-bf16 MFMA (8 waves x 2 n-tiles) ----
    int w = tid >> 6, l = tid & 63;
    int la = l & 15, g4 = l >> 4;
    int mtile = w & 3, nt2 = (w >> 2) * 2;   // n-tiles nt2, nt2+1

    BU ahi[2], alo[2];
    #pragma unroll
    for (int kf = 0; kf < 2; ++kf) {
        const unsigned* hp = &sHu[(mtile * 16 + la) * 76 + kf * 32 + g4 * 8];
        uint4 a0 = *(const uint4*)hp;
        uint4 a1 = *(const uint4*)(hp + 4);
        unsigned wv8[8] = {a0.x, a0.y, a0.z, a0.w, a1.x, a1.y, a1.z, a1.w};
        #pragma unroll
        for (int e = 0; e < 8; ++e) {
            ahi[kf].u[e] = (unsigned short)wv8[e];
            alo[kf].u[e] = (unsigned short)(wv8[e] >> 16);
        }
    }

    unsigned short* Pus = (unsigned short*)P16b;
    #pragma unroll
    for (int j = 0; j < 2; ++j) {
        int ntile = nt2 + j;
        f32x4 acc = {0.f, 0.f, 0.f, 0.f};
        #pragma unroll
        for (int kf = 0; kf < 2; ++kf) {
            const unsigned short* Wq = Wf + (size_t)(32 + (ntile * 2 + kf) * 2) * 512;
            bf16x8 bhi = *(const bf16x8*)&Wq[l * 8];
            bf16x8 blo = *(const bf16x8*)&Wq[512 + l * 8];
            acc = __builtin_amdgcn_mfma_f32_16x16x32_bf16(ahi[kf].v, bhi, acc, 0, 0, 0);
            acc = __builtin_amdgcn_mfma_f32_16x16x32_bf16(alo[kf].v, bhi, acc, 0, 0, 0);
            acc = __builtin_amdgcn_mfma_f32_16x16x32_bf16(ahi[kf].v, blo, acc, 0, 0, 0);
        }
        int col = ntile * 16 + la;
        if (col < 32) {
            #pragma unroll
            for (int rr = 0; rr < 4; ++rr) {
                int node = nodeBase + mtile * 16 + g4 * 4 + rr;
                if (node < N)
                    Pus[(size_t)node * 32 + col] = f2bf(acc[rr]);
            }
        } else {
            float bb = b2[col - 32];
            #pragma unroll
            for (int rr = 0; rr < 4; ++rr) {
                int node = nodeBase + mtile * 16 + g4 * 4 + rr;
                if (node < N)
                    Qout[(size_t)node * 32 + (col - 32)] = acc[rr] + bb;
            }
        }
    }
}

// --- A2: h = mean(P[neigh]) + Q -> out_h ; trust head (adj walk) ------------
__global__ __launch_bounds__(256) void k_a2(
    const int2* __restrict__ nodeOff, const int* __restrict__ adj,
    const unsigned* __restrict__ P16b, const float* __restrict__ Q,
    const float* __restrict__ Wt1, const float* __restrict__ bt1,
    const float* __restrict__ Wt2, const float* __restrict__ bt2,
    float* __restrict__ out_h, float* __restrict__ out_trust, int N)
{
    __shared__ float sWt1[32 * 16];
    __shared__ float sWt2[16];
    for (int i = threadIdx.x; i < 512; i += 256) sWt1[i] = Wt1[i];
    if (threadIdx.x < 16) sWt2[threadIdx.x] = Wt2[threadIdx.x];
    __syncthreads();

    int n = blockIdx.x * 16 + (threadIdx.x >> 4);
    int lane = threadIdx.x & 15;
    if (n >= N) return;

    int2 od = nodeOff[n];
    int beg = od.x, end = od.x + od.y;
    float lo[8] = {0,0,0,0,0,0,0,0}, hi[8] = {0,0,0,0,0,0,0,0};
    int i = beg;
    for (; i + 8 <= end; i += 8) {
        int s[8];
        #pragma unroll
        for (int j = 0; j < 8; ++j) s[j] = adj[i + j];
        #pragma unroll
        for (int j = 0; j < 8; ++j) {
            unsigned w = P16b[(unsigned)s[j] * 16u + lane];
            lo[j] += bflo(w); hi[j] += bfhi(w);
        }
    }
    for (; i < end; ++i) {
        unsigned w = P16b[(unsigned)adj[i] * 16u + lane];
        lo[0] += bflo(w); hi[0] += bfhi(w);
    }
    float invd = (od.y > 0) ? 1.0f / (float)od.y : 1.0f;
    float mlo = (((lo[0]+lo[1])+(lo[2]+lo[3])) + ((lo[4]+lo[5])+(lo[6]+lo[7]))) * invd;
    float mhi = (((hi[0]+hi[1])+(hi[2]+hi[3])) + ((hi[4]+hi[5])+(hi[6]+hi[7]))) * invd;

    float2 qv = ((const float2*)Q)[(size_t)n * 16 + lane];
    float hx = mlo + qv.x;
    float hy = mhi + qv.y;

    ((float2*)out_h)[(size_t)n * 16 + lane] = make_float2(hx, hy);

    float t = bt1[lane];
    #pragma unroll
    for (int k = 0; k < 16; ++k) {
        float hlo = __shfl(hx, k, 16);
        float hhi = __shfl(hy, k, 16);
        t += hlo * sWt1[(2 * k) * 16 + lane] + hhi * sWt1[(2 * k + 1) * 16 + lane];
    }
    t = fmaxf(t, 0.0f);
    float z = t * sWt2[lane];
    z += __shfl_xor(z, 1);
    z += __shfl_xor(z, 2);
    z += __shfl_xor(z, 4);
    z += __shfl_xor(z, 8);
    if (lane == 0) out_trust[n] = 1.0f / (1.0f + expf(-(z + bt2[0])));
}

// ---------------------------------------------------------------------------

extern "C" void kernel_launch(void* const* d_in, const int* in_sizes, int n_in,
                              void* d_out, int out_size, void* d_ws, size_t ws_size,
                              hipStream_t stream)
{
    const float* x   = (const float*)d_in[0];
    const int*   ei  = (const int*)d_in[1];
    const float* Wl1 = (const float*)d_in[2];
    const float* Wr1 = (const float*)d_in[3];
    const float* b1  = (const float*)d_in[4];
    const float* Wl2 = (const float*)d_in[5];
    const float* Wr2 = (const float*)d_in[6];
    const float* b2  = (const float*)d_in[7];
    const float* Wt1 = (const float*)d_in[8];
    const float* bt1 = (const float*)d_in[9];
    const float* Wt2 = (const float*)d_in[10];
    const float* bt2 = (const float*)d_in[11];

    const int N = in_sizes[0] / 64;   // 100000
    const int E = in_sizes[1] / 2;    // 1600000
    const int* src = ei;
    const int* dst = ei + E;

    // Workspace layout (all segments 64B-aligned)
    unsigned* pairs  = (unsigned*)d_ws;                        // NBUCK*BCAP (~9.6MB)
    unsigned* u16b   = pairs + (size_t)NBUCK * BCAP;           // N*32 (bf16 x2)
    float*    v      = (float*)(u16b + (size_t)N * 32);        // N*64
    unsigned* P16b   = (unsigned*)(v + (size_t)N * 64);        // N*16 (bf16 x2)
    float*    Q      = (float*)(P16b + (size_t)N * 16);        // N*32
    int2*     nodeOff= (int2*)(Q + (size_t)N * 32);            // N
    int*      adj    = (int*)(nodeOff + N);                    // NBUCK*BCAP
    int*      gcnt   = adj + (size_t)NBUCK * BCAP;             // 2048 (1563 used)
    unsigned short* Wf = (unsigned short*)(gcnt + 2048);       // 48 planes x 512
    // total ~78 MB

    k_w<<<1, 256, 0, stream>>>(Wl1, Wr1, Wl2, Wr2, Wf, gcnt);

    const int GB  = (N + 63) / 64;               // 1563 gemm1 tiles
    const int BKB = (E + BKCHUNK - 1) / BKCHUNK; // 391 bucket chunks
    const int GP  = (GB + 3) / 4;                // 391 tile-pair pairs (2 tiles/blk)
    int grp = GP > BKB ? GP : BKB;               // 391
    k_m1<<<3 * grp, 512, 0, stream>>>(x, Wf, b1, u16b, v,
                                      src, dst, gcnt, pairs, N, E, GB, BKB);
    k_m2<<<NBUCK, 512, 0, stream>>>(pairs, gcnt, u16b, v, Wf, b2,
                                    P16b, Q, nodeOff, adj, N);

    float* out_h     = (float*)d_out;
    float* out_trust = out_h + (size_t)N * 32;
    k_a2<<<(N + 15) / 16, 256, 0, stream>>>(nodeOff, adj, P16b, Q,
                                            Wt1, bt1, Wt2, bt2,
                                            out_h, out_trust, N);
}

// Round 16
// 202.330 us; speedup vs baseline: 1.0305x; 1.0305x over previous
//
#include <hip/hip_runtime.h>
#include <math.h>

// ---------------------------------------------------------------------------
// CommunityTrustGNN: 2-layer GraphSAGE (mean agg) + trust MLP head
// N=100000 nodes, E=1600000 edges, dims 64 -> 64 -> 32 -> (16 -> 1)
//
// Round 27 = round-25 (verified 206.6us; r26's fill-pipelining was neutral
// noise, reverted) + k_a2 ported to the r25-proven wide-gather pattern:
//  * k_a2: 8 lanes x uint2 per 64B P16b row (was 16 lanes x 1 dword) ->
//    8 edges per wave-instruction (was 4); serial neighbor walk, no
//    cross-lane ops in the hot loop. 32 nodes/block (3125 blocks, loop
//    depth ~4+tail — not r23's shallow-loop failure). Head: 2 cols/lane,
//    width-8 shfl broadcast, width-8 xor reduce.
//  * k_w, k_m1, k_m2: round-25 verbatim (the 206.6us config).
// Known fixed overhead: harness 256MB fillBuffer at 75% HBM (~45us) inside
// the measured window — practical floor ~200us.
// ---------------------------------------------------------------------------

#define NBUCK   1563     // ceil(100000/64) buckets of 64 dst nodes
#define BCAP    1536     // bucket capacity (mean 1024, +16 sigma)
#define BKCHUNK 4096     // edges per bucket-chunk block in M1

typedef __attribute__((ext_vector_type(8))) __bf16 bf16x8;
typedef __attribute__((ext_vector_type(4))) float  f32x4;

union BU { bf16x8 v; unsigned short u[8]; };

// bf16 helpers (round-to-nearest-even pack, exact unpack)
__device__ inline unsigned short f2bf(float x) {
    unsigned u = __float_as_uint(x);
    unsigned r = u + 0x7fffu + ((u >> 16) & 1u);
    return (unsigned short)(r >> 16);
}
__device__ inline float bflo(unsigned u) { return __uint_as_float(u << 16); }
__device__ inline float bfhi(unsigned u) { return __uint_as_float(u & 0xffff0000u); }
__device__ inline float bf2f(unsigned short h) { return __uint_as_float((unsigned)h << 16); }
// pack value as (bf16hi | bf16lo<<16) for split-bf16 A-fragments
__device__ inline unsigned packhl(float x) {
    unsigned short h = f2bf(x);
    unsigned short l = f2bf(x - bf2f(h));
    return (unsigned)h | ((unsigned)l << 16);
}

// --- W: precompute fragment-ordered bf16 hi/lo weight planes; zero gcnt -----
__global__ __launch_bounds__(256) void k_w(
    const float* __restrict__ Wl1, const float* __restrict__ Wr1,
    const float* __restrict__ Wl2, const float* __restrict__ Wr2,
    unsigned short* __restrict__ Wf, int* __restrict__ gcnt)
{
    int tid = threadIdx.x;
    for (int i = tid; i < 2048; i += 256) gcnt[i] = 0;
    for (int idx = tid; idx < 1536; idx += 256) {
        unsigned short hi8[8], lo8[8];
        int base;
        if (idx < 1024) {
            int q = idx >> 6;                 // 0..15: (pass,nf,kf)
            int l = idx & 63;
            int pass = q >> 3, nf = (q >> 1) & 3, kf = q & 1;
            const float* W = pass ? Wr1 : Wl1;
            int col  = nf * 16 + (l & 15);
            int krow = kf * 32 + (l >> 4) * 8;
            #pragma unroll
            for (int e = 0; e < 8; ++e) {
                float w = W[(krow + e) * 64 + col];
                unsigned short h = f2bf(w);
                hi8[e] = h;
                lo8[e] = f2bf(w - bf2f(h));
            }
            base = (q * 2) * 512 + l * 8;
        } else {
            int i2 = idx - 1024;
            int q2 = i2 >> 6;                 // 0..7: (ntile,kf)
            int l = i2 & 63;
            int ntile = q2 >> 1, kf = q2 & 1;
            int col  = ntile * 16 + (l & 15); // 0..63 over concat(Wl2,Wr2)
            const float* W = (col < 32) ? Wl2 : Wr2;
            int c = col & 31;
            int krow = kf * 32 + (l >> 4) * 8;
            #pragma unroll
            for (int e = 0; e < 8; ++e) {
                float w = W[(krow + e) * 32 + c];
                unsigned short h = f2bf(w);
                hi8[e] = h;
                lo8[e] = f2bf(w - bf2f(h));
            }
            base = (32 + q2 * 2) * 512 + l * 8;
        }
        #pragma unroll
        for (int e = 0; e < 8; ++e) {
            Wf[base + e]       = hi8[e];
            Wf[base + 512 + e] = lo8[e];
        }
    }
}

// --- M1: interleaved gemm1 tile-pairs + bucket-scatter chunks ---------------
// blockIdx%3==2 -> scatter chunk (blockIdx/3); else tile-pair p=2*(b/3)+(b%3),
// tiles 2p+(wave>>2).
__global__ __launch_bounds__(512) void k_m1(
    const float* __restrict__ x,
    const unsigned short* __restrict__ Wf, const float* __restrict__ b1,
    unsigned* __restrict__ u16b, float* __restrict__ v,
    const int* __restrict__ src, const int* __restrict__ dst,
    int* __restrict__ gcnt, unsigned* __restrict__ pairs,
    int N, int E, int GB, int BKB)
{
    __shared__ int hist[NBUCK];           // 6252B (scatter blocks only)
    int tid = threadIdx.x;
    int g = blockIdx.x / 3, r3 = blockIdx.x % 3;

    if (r3 == 2) {
        // ---------------- bucket-scatter path (512 thr, 8 edges/thr) ------
        if (g >= BKB) return;
        int e0 = g * BKCHUNK;
        int e1 = min(e0 + BKCHUNK, E);

        // load edges once into regs
        int d[8], s[8], ne = 0;
        for (int e = e0 + tid; e < e1; e += 512) {
            d[ne] = dst[e];
            s[ne] = src[e];
            ++ne;
        }

        for (int i = tid; i < NBUCK; i += 512) hist[i] = 0;
        __syncthreads();
        for (int k = 0; k < ne; ++k)
            atomicAdd(&hist[((unsigned)d[k]) >> 6], 1);
        __syncthreads();
        // pipelined reservation: 4 independent atomics issued back-to-back
        int cnt[4], base[4];
        #pragma unroll
        for (int t = 0; t < 4; ++t) {
            int i = tid + t * 512;
            cnt[t] = (i < NBUCK) ? hist[i] : 0;
        }
        #pragma unroll
        for (int t = 0; t < 4; ++t) {
            int i = tid + t * 512;
            base[t] = (i < NBUCK) ? atomicAdd(&gcnt[i], cnt[t]) : 0;
        }
        #pragma unroll
        for (int t = 0; t < 4; ++t) {
            int i = tid + t * 512;
            if (i < NBUCK) hist[i] = i * BCAP + base[t];
        }
        __syncthreads();
        for (int k = 0; k < ne; ++k) {
            int t = d[k];
            int b = ((unsigned)t) >> 6;
            int pos = atomicAdd(&hist[b], 1);
            if (pos < (b + 1) * BCAP)   // overflow clamp (16-sigma margin)
                pairs[pos] = (unsigned)s[k] | ((unsigned)(t & 63) << 17);
        }
        return;
    }

    // ---------------- gemm1 path: split-bf16 MFMA, no LDS, 2 tiles --------
    int p = 2 * g + r3;
    int wave = tid >> 6;
    int tile = 2 * p + (wave >> 2);
    if (tile >= GB) return;
    int nblk = tile * 64;

    int l  = tid & 63;
    int wv = wave & 3;                  // row-block within tile
    int la = l & 15,   g4 = l >> 4;     // col-within-16, k-group
    int arow = nblk + wv * 16 + la;     // A row for this lane
    bool rowOK = (arow < N);

    // A fragments from global (16 rows x 128B contiguous per k-half)
    BU ahi[2], alo[2];
    #pragma unroll
    for (int kf = 0; kf < 2; ++kf) {
        float xv[8];
        if (rowOK) {
            const float* xp = &x[(size_t)arow * 64 + kf * 32 + g4 * 8];
            float4 p0 = *(const float4*)xp;
            float4 p1 = *(const float4*)(xp + 4);
            xv[0] = p0.x; xv[1] = p0.y; xv[2] = p0.z; xv[3] = p0.w;
            xv[4] = p1.x; xv[5] = p1.y; xv[6] = p1.z; xv[7] = p1.w;
        } else {
            #pragma unroll
            for (int e = 0; e < 8; ++e) xv[e] = 0.0f;
        }
        #pragma unroll
        for (int e = 0; e < 8; ++e) {
            unsigned short h = f2bf(xv[e]);
            ahi[kf].u[e] = h;
            alo[kf].u[e] = f2bf(xv[e] - bf2f(h));
        }
    }

    unsigned short* u16 = (unsigned short*)u16b;

    #pragma unroll
    for (int pass = 0; pass < 2; ++pass) {
        #pragma unroll
        for (int nf = 0; nf < 4; ++nf) {
            int n0 = nf * 16;
            f32x4 acc = {0.f, 0.f, 0.f, 0.f};
            #pragma unroll
            for (int kf = 0; kf < 2; ++kf) {
                int q2 = ((pass * 4 + nf) * 2 + kf) * 2;
                bf16x8 bhi = *(const bf16x8*)&Wf[(q2 + 0) * 512 + l * 8];
                bf16x8 blo = *(const bf16x8*)&Wf[(q2 + 1) * 512 + l * 8];
                acc = __builtin_amdgcn_mfma_f32_16x16x32_bf16(ahi[kf].v, bhi, acc, 0, 0, 0);
                acc = __builtin_amdgcn_mfma_f32_16x16x32_bf16(alo[kf].v, bhi, acc, 0, 0, 0);
                acc = __builtin_amdgcn_mfma_f32_16x16x32_bf16(ahi[kf].v, blo, acc, 0, 0, 0);
            }
            // D: col = la, row = g4*4 + r  (m89-verified layout)
            if (pass == 0) {
                #pragma unroll
                for (int rr = 0; rr < 4; ++rr) {
                    int nd = nblk + wv * 16 + g4 * 4 + rr;
                    if (nd < N)
                        u16[(size_t)nd * 64 + n0 + la] = f2bf(acc[rr]);
                }
            } else {
                float bb = b1[n0 + la];
                #pragma unroll
                for (int rr = 0; rr < 4; ++rr) {
                    int nd = nblk + wv * 16 + g4 * 4 + rr;
                    if (nd < N)
                        v[(size_t)nd * 64 + n0 + la] = acc[rr] + bb;
                }
            }
        }
    }
}

// --- M2: local-CSR (persisted) + agg1 + gemm2(MFMA). Block = 64-node bucket.
// Phase A: 32 groups x 16 lanes x 2 nodes; uint2 row-slice per lane (4
//          features owned per lane), serial neighbor walk, no cross-lane.
__global__ __launch_bounds__(512) void k_m2(
    const unsigned* __restrict__ pairs, const int* __restrict__ gcnt,
    const unsigned* __restrict__ u16b, const float* __restrict__ v,
    const unsigned short* __restrict__ Wf, const float* __restrict__ b2,
    unsigned* __restrict__ P16b, float* __restrict__ Qout,
    int2* __restrict__ nodeOff, int* __restrict__ adjG, int N)
{
    __shared__ unsigned sHu[64 * 76]; // 19456B packed h tile, stride 76
    __shared__ int   sAdj[BCAP];      // 6144B
    __shared__ int   sOff[65];
    __shared__ int   sCur[64];
    int tid = threadIdx.x;
    int b = blockIdx.x;
    int nodeBase = b * 64;
    int base = b * BCAP;
    int count = min(gcnt[b], BCAP);
    const unsigned* pp = pairs + (size_t)b * BCAP;

    if (tid < 64) sCur[tid] = 0;
    __syncthreads();

    // ---- local CSR: histogram -> scan -> fill ----
    for (int j = tid; j < count; j += 512)
        atomicAdd(&sCur[(pp[j] >> 17) & 63], 1);
    __syncthreads();
    if (tid < 64) {
        int c = sCur[tid];
        int incl = c;
        #pragma unroll
        for (int off = 1; off < 64; off <<= 1) {
            int t = __shfl_up(incl, off);
            if (tid >= off) incl += t;
        }
        sOff[tid] = incl - c;
        if (tid == 63) sOff[64] = incl;
    }
    __syncthreads();
    if (tid < 64) {
        sCur[tid] = sOff[tid];
        int node = nodeBase + tid;
        if (node < N)
            nodeOff[node] = make_int2(base + sOff[tid], sOff[tid + 1] - sOff[tid]);
    }
    __syncthreads();
    for (int j = tid; j < count; j += 512) {
        unsigned e = pp[j];
        int pos = atomicAdd(&sCur[(e >> 17) & 63], 1);
        sAdj[pos] = (int)(e & 0x1FFFFu);
    }
    __syncthreads();
    // persist adj for k_a2 (coalesced burst)
    for (int j = tid; j < count; j += 512) adjG[base + j] = sAdj[j];

    // ---- Phase A: 32 groups x 16 lanes, 2 nodes each, uint2 serial walk ----
    int gr = tid >> 4, lane = tid & 15;
    for (int r = 0; r < 2; ++r) {
        int nl = gr * 2 + r;
        int node = nodeBase + nl;
        float h0 = 0.0f, h1 = 0.0f, h2 = 0.0f, h3 = 0.0f;
        if (node < N) {
            int beg = sOff[nl], end = sOff[nl + 1];
            float a0[4] = {0,0,0,0}, a1[4] = {0,0,0,0};
            float a2[4] = {0,0,0,0}, a3[4] = {0,0,0,0};
            unsigned fo = 2u * (unsigned)lane;
            int i = beg;
            for (; i + 4 <= end; i += 4) {
                int s[4];
                #pragma unroll
                for (int j = 0; j < 4; ++j) s[j] = sAdj[i + j];
                #pragma unroll
                for (int j = 0; j < 4; ++j) {
                    uint2 w = *(const uint2*)&u16b[(unsigned)s[j] * 32u + fo];
                    a0[j] += bflo(w.x); a1[j] += bfhi(w.x);
                    a2[j] += bflo(w.y); a3[j] += bfhi(w.y);
                }
            }
            for (; i < end; ++i) {
                uint2 w = *(const uint2*)&u16b[(unsigned)sAdj[i] * 32u + fo];
                a0[0] += bflo(w.x); a1[0] += bfhi(w.x);
                a2[0] += bflo(w.y); a3[0] += bfhi(w.y);
            }
            float m0 = (a0[0] + a0[1]) + (a0[2] + a0[3]);
            float m1 = (a1[0] + a1[1]) + (a1[2] + a1[3]);
            float m2 = (a2[0] + a2[1]) + (a2[2] + a2[3]);
            float m3 = (a3[0] + a3[1]) + (a3[2] + a3[3]);
            int deg = end - beg;
            float invd = (deg > 0) ? 1.0f / (float)deg : 1.0f;
            float4 vv = *(const float4*)&v[(size_t)node * 64 + 4 * lane];
            h0 = fmaxf(m0 * invd + vv.x, 0.0f);
            h1 = fmaxf(m1 * invd + vv.y, 0.0f);
            h2 = fmaxf(m2 * invd + vv.z, 0.0f);
            h3 = fmaxf(m3 * invd + vv.w, 0.0f);
        }
        // features 4*lane .. 4*lane+3 packed hi|lo
        *(uint4*)&sHu[nl * 76 + 4 * lane] =
            make_uint4(packhl(h0), packhl(h1), packhl(h2), packhl(h3));
    }
    __syncthreads();

    // ---- Phase B: 64x64 split-bf16 MFMA (8 waves x 2 n-tiles) ----
    int w = tid >> 6, l = tid & 63;
    int la = l & 15, g4 = l >> 4;
    int mtile = w & 3, nt2 = (w >> 2) * 2;   // n-tiles nt2, nt2+1

    BU ahi[2], alo[2];
    #pragma unroll
    for (int kf = 0; kf < 2; ++kf) {
        const unsigned* hp = &sHu[(mtile * 16 + la) * 76 + kf * 32 + g4 * 8];
        uint4 a0 = *(const uint4*)hp;
        uint4 a1 = *(const uint4*)(hp + 4);
        unsigned wv8[8] = {a0.x, a0.y, a0.z, a0.w, a1.x, a1.y, a1.z, a1.w};
        #pragma unroll
        for (int e = 0; e < 8; ++e) {
            ahi[kf].u[e] = (unsigned short)wv8[e];
            alo[kf].u[e] = (unsigned short)(wv8[e] >> 16);
        }
    }

    unsigned short* Pus = (unsigned short*)P16b;
    #pragma unroll
    for (int j = 0; j < 2; ++j) {
        int ntile = nt2 + j;
        f32x4 acc = {0.f, 0.f, 0.f, 0.f};
        #pragma unroll
        for (int kf = 0; kf < 2; ++kf) {
            const unsigned short* Wq = Wf + (size_t)(32 + (ntile * 2 + kf) * 2) * 512;
            bf16x8 bhi = *(const bf16x8*)&Wq[l * 8];
            bf16x8 blo = *(const bf16x8*)&Wq[512 + l * 8];
            acc = __builtin_amdgcn_mfma_f32_16x16x32_bf16(ahi[kf].v, bhi, acc, 0, 0, 0);
            acc = __builtin_amdgcn_mfma_f32_16x16x32_bf16(alo[kf].v, bhi, acc, 0, 0, 0);
            acc = __builtin_amdgcn_mfma_f32_16x16x32_bf16(ahi[kf].v, blo, acc, 0, 0, 0);
        }
        int col = ntile * 16 + la;
        if (col < 32) {
            #pragma unroll
            for (int rr = 0; rr < 4; ++rr) {
                int node = nodeBase + mtile * 16 + g4 * 4 + rr;
                if (node < N)
                    Pus[(size_t)node * 32 + col] = f2bf(acc[rr]);
            }
        } else {
            float bb = b2[col - 32];
            #pragma unroll
            for (int rr = 0; rr < 4; ++rr) {
                int node = nodeBase + mtile * 16 + g4 * 4 + rr;
                if (node < N)
                    Qout[(size_t)node * 32 + (col - 32)] = acc[rr] + bb;
            }
        }
    }
}

// --- A2: 8 lanes x uint2 per node row; serial walk; head 2 cols/lane --------
__global__ __launch_bounds__(256) void k_a2(
    const int2* __restrict__ nodeOff, const int* __restrict__ adj,
    const unsigned* __restrict__ P16b, const float* __restrict__ Q,
    const float* __restrict__ Wt1, const float* __restrict__ bt1,
    const float* __restrict__ Wt2, const float* __restrict__ bt2,
    float* __restrict__ out_h, float* __restrict__ out_trust, int N)
{
    __shared__ float sWt1[32 * 16];
    __shared__ float sWt2[16];
    for (int i = threadIdx.x; i < 512; i += 256) sWt1[i] = Wt1[i];
    if (threadIdx.x < 16) sWt2[threadIdx.x] = Wt2[threadIdx.x];
    __syncthreads();

    int n = blockIdx.x * 32 + (threadIdx.x >> 3);
    int lane = threadIdx.x & 7;
    if (n >= N) return;

    int2 od = nodeOff[n];
    int beg = od.x, end = od.x + od.y;
    float a0[4] = {0,0,0,0}, a1[4] = {0,0,0,0};
    float a2[4] = {0,0,0,0}, a3[4] = {0,0,0,0};
    unsigned fo = 2u * (unsigned)lane;
    int i = beg;
    for (; i + 4 <= end; i += 4) {
        int s[4];
        #pragma unroll
        for (int j = 0; j < 4; ++j) s[j] = adj[i + j];
        #pragma unroll
        for (int j = 0; j < 4; ++j) {
            uint2 w = *(const uint2*)&P16b[(unsigned)s[j] * 16u + fo];
            a0[j] += bflo(w.x); a1[j] += bfhi(w.x);
            a2[j] += bflo(w.y); a3[j] += bfhi(w.y);
        }
    }
    for (; i < end; ++i) {
        uint2 w = *(const uint2*)&P16b[(unsigned)adj[i] * 16u + fo];
        a0[0] += bflo(w.x); a1[0] += bfhi(w.x);
        a2[0] += bflo(w.y); a3[0] += bfhi(w.y);
    }
    float invd = (od.y > 0) ? 1.0f / (float)od.y : 1.0f;
    float m0 = ((a0[0] + a0[1]) + (a0[2] + a0[3])) * invd;
    float m1 = ((a1[0] + a1[1]) + (a1[2] + a1[3])) * invd;
    float m2 = ((a2[0] + a2[1]) + (a2[2] + a2[3])) * invd;
    float m3 = ((a3[0] + a3[1]) + (a3[2] + a3[3])) * invd;

    float4 q4 = *(const float4*)&Q[(size_t)n * 32 + 4 * lane];
    float h0 = m0 + q4.x;
    float h1 = m1 + q4.y;
    float h2 = m2 + q4.z;
    float h3 = m3 + q4.w;

    *(float4*)&out_h[(size_t)n * 32 + 4 * lane] = make_float4(h0, h1, h2, h3);

    // head: lane handles output cols 2*lane, 2*lane+1; h_k owned by lane k>>2
    int j0 = 2 * lane, j1 = j0 + 1;
    float t0 = bt1[j0], t1 = bt1[j1];
    #pragma unroll
    for (int k = 0; k < 32; ++k) {
        int srcl = k >> 2;
        float hk = ((k & 3) == 0) ? __shfl(h0, srcl, 8)
                 : ((k & 3) == 1) ? __shfl(h1, srcl, 8)
                 : ((k & 3) == 2) ? __shfl(h2, srcl, 8)
                                  : __shfl(h3, srcl, 8);
        t0 = fmaf(hk, sWt1[k * 16 + j0], t0);
        t1 = fmaf(hk, sWt1[k * 16 + j1], t1);
    }
    t0 = fmaxf(t0, 0.0f);
    t1 = fmaxf(t1, 0.0f);
    float z = t0 * sWt2[j0] + t1 * sWt2[j1];
    z += __shfl_xor(z, 1, 8);
    z += __shfl_xor(z, 2, 8);
    z += __shfl_xor(z, 4, 8);
    if (lane == 0) out_trust[n] = 1.0f / (1.0f + expf(-(z + bt2[0])));
}

// ---------------------------------------------------------------------------

extern "C" void kernel_launch(void* const* d_in, const int* in_sizes, int n_in,
                              void* d_out, int out_size, void* d_ws, size_t ws_size,
                              hipStream_t stream)
{
    const float* x   = (const float*)d_in[0];
    const int*   ei  = (const int*)d_in[1];
    const float* Wl1 = (const float*)d_in[2];
    const float* Wr1 = (const float*)d_in[3];
    const float* b1  = (const float*)d_in[4];
    const float* Wl2 = (const float*)d_in[5];
    const float* Wr2 = (const float*)d_in[6];
    const float* b2  = (const float*)d_in[7];
    const float* Wt1 = (const float*)d_in[8];
    const float* bt1 = (const float*)d_in[9];
    const float* Wt2 = (const float*)d_in[10];
    const float* bt2 = (const float*)d_in[11];

    const int N = in_sizes[0] / 64;   // 100000
    const int E = in_sizes[1] / 2;    // 1600000
    const int* src = ei;
    const int* dst = ei + E;

    // Workspace layout (all segments 64B-aligned)
    unsigned* pairs  = (unsigned*)d_ws;                        // NBUCK*BCAP (~9.6MB)
    unsigned* u16b   = pairs + (size_t)NBUCK * BCAP;           // N*32 (bf16 x2)
    float*    v      = (float*)(u16b + (size_t)N * 32);        // N*64
    unsigned* P16b   = (unsigned*)(v + (size_t)N * 64);        // N*16 (bf16 x2)
    float*    Q      = (float*)(P16b + (size_t)N * 16);        // N*32
    int2*     nodeOff= (int2*)(Q + (size_t)N * 32);            // N
    int*      adj    = (int*)(nodeOff + N);                    // NBUCK*BCAP
    int*      gcnt   = adj + (size_t)NBUCK * BCAP;             // 2048 (1563 used)
    unsigned short* Wf = (unsigned short*)(gcnt + 2048);       // 48 planes x 512
    // total ~78 MB

    k_w<<<1, 256, 0, stream>>>(Wl1, Wr1, Wl2, Wr2, Wf, gcnt);

    const int GB  = (N + 63) / 64;               // 1563 gemm1 tiles
    const int BKB = (E + BKCHUNK - 1) / BKCHUNK; // 391 bucket chunks
    const int GP  = (GB + 3) / 4;                // 391 tile-pair pairs (2 tiles/blk)
    int grp = GP > BKB ? GP : BKB;               // 391
    k_m1<<<3 * grp, 512, 0, stream>>>(x, Wf, b1, u16b, v,
                                      src, dst, gcnt, pairs, N, E, GB, BKB);
    k_m2<<<NBUCK, 512, 0, stream>>>(pairs, gcnt, u16b, v, Wf, b2,
                                    P16b, Q, nodeOff, adj, N);

    float* out_h     = (float*)d_out;
    float* out_trust = out_h + (size_t)N * 32;
    k_a2<<<(N + 31) / 32, 256, 0, stream>>>(nodeOff, adj, P16b, Q,
                                            Wt1, bt1, Wt2, bt2,
                                            out_h, out_trust, N);
}